// Round 1
// baseline (242.379 us; speedup 1.0000x reference)
//
#include <hip/hip_runtime.h>
#include <hip/hip_bf16.h>
#include <math.h>

#define BATCH 8
#define SQ 2048
#define SK 2048
#define DD 512
#define DV 512
#define RP 40   // LDS row pitch in shorts (80 B). Frag reads: 8-bank spread from 20*row mod 32.

typedef short bf16x8_t __attribute__((ext_vector_type(8)));
typedef float f32x4_t __attribute__((ext_vector_type(4)));

// packed RTNE fp32x2 -> bf16x2 (v_cvt_pk_bf16_f32)
__device__ __forceinline__ unsigned int pk_bf16(float a, float b) {
    __hip_bfloat162 h = __float22bfloat162_rn(float2{a, b});
    unsigned int u;
    __builtin_memcpy(&u, &h, 4);
    return u;
}
__device__ __forceinline__ float from_hi(unsigned int u) {
    return __builtin_bit_cast(float, u);
}

// ---------------------------------------------------------------------------
// Kernel 1: fp32 partials of K^T V (un-scaled), t-split by 4.
// Mpart: [ts(4)][b(8)][d(512)][v(512)] fp32 == 32 MB, lives in d_out.
// 128x128 tile, BK=32.
// NEW this round:
//  - raw s_barrier (no vmcnt(0) drain) + distance-2 register prefetch:
//    global loads for tile i+2 stay in flight across 2 barriers; compiler
//    emits counted vmcnt(8) at the stage that consumes tile i.
//  - float4 global loads (8 dwordx4/thread/step instead of 32 dword) with
//    (t-quad, d-quad) thread ownership.
//  - b64 LDS writes with XOR col swizzle  col ^= ((row>>3)&3)<<4  -> 4-way
//    write conflicts (same as old b32 pattern, half the instructions);
//    frag reads apply the same XOR, base bank spread unchanged.
//  - s_setprio(1) around the MFMA cluster (T5).
// 3-term split MFMA: Kh*Vh + Kh*Vl + Kl*Vh.
// ---------------------------------------------------------------------------
__global__ __launch_bounds__(256) void ktv_mfma(const float* __restrict__ Kp,
                                                const float* __restrict__ Vp,
                                                float* __restrict__ Mpart) {
    const int b  = blockIdx.z & 7;
    const int ts = blockIdx.z >> 3;
    const int d0 = blockIdx.x * 128;
    const int v0 = blockIdx.y * 128;
    const float* Kb = Kp + (size_t)b * SK * DD;
    const float* Vb = Vp + (size_t)b * SK * DV;

    __shared__ __align__(16) unsigned short Kh[128 * RP], Kl[128 * RP],
                                            Vh[128 * RP], Vl[128 * RP];

    const int tid  = threadIdx.x;
    const int lane = tid & 63;
    const int w    = tid >> 6;
    const int wd   = (w & 1) * 64;
    const int wv   = (w >> 1) * 64;
    const int tq   = tid >> 5;   // 0..7  t-quad (4 consecutive t)
    const int dq   = tid & 31;   // 0..31 d-quad (4 consecutive d)

    f32x4_t acc[4][4];
#pragma unroll
    for (int i = 0; i < 4; ++i)
#pragma unroll
        for (int j = 0; j < 4; ++j) acc[i][j] = (f32x4_t){0.f, 0.f, 0.f, 0.f};

    const int tb = ts * 512;
    // swizzled column byte for staging: constant per thread
    // (row>>3 == dq>>1 for all dd in 0..3 since row = 4*dq+dd)
    const int st_col = (8 * tq) ^ (((dq >> 1) & 3) << 4);

    // distance-2 prefetch buffers (named, constant-indexed -> registers)
    f32x4_t kA[4], vA[4], kB[4], vB[4];

    auto load_t = [&](f32x4_t* kr, f32x4_t* vr, int t0l) {
#pragma unroll
        for (int r = 0; r < 4; ++r) {
            const size_t gr = (size_t)(tb + t0l + 4 * tq + r);
            kr[r] = *(const f32x4_t*)&Kb[gr * DD + d0 + 4 * dq];
            vr[r] = *(const f32x4_t*)&Vb[gr * DV + v0 + 4 * dq];
        }
    };

    auto stage_t = [&](const f32x4_t* kr, const f32x4_t* vr) {
#pragma unroll
        for (int dd = 0; dd < 4; ++dd) {
            const int boff = (4 * dq + dd) * (2 * RP) + st_col;
            {
                const unsigned int h0 = pk_bf16(kr[0][dd], kr[1][dd]);
                const unsigned int h1 = pk_bf16(kr[2][dd], kr[3][dd]);
                const float r0 = kr[0][dd] - from_hi(h0 << 16);
                const float r1 = kr[1][dd] - from_hi(h0 & 0xFFFF0000u);
                const float r2 = kr[2][dd] - from_hi(h1 << 16);
                const float r3 = kr[3][dd] - from_hi(h1 & 0xFFFF0000u);
                *(uint2*)((char*)Kh + boff) = make_uint2(h0, h1);
                *(uint2*)((char*)Kl + boff) = make_uint2(pk_bf16(r0, r1), pk_bf16(r2, r3));
            }
            {
                const unsigned int h0 = pk_bf16(vr[0][dd], vr[1][dd]);
                const unsigned int h1 = pk_bf16(vr[2][dd], vr[3][dd]);
                const float r0 = vr[0][dd] - from_hi(h0 << 16);
                const float r1 = vr[1][dd] - from_hi(h0 & 0xFFFF0000u);
                const float r2 = vr[2][dd] - from_hi(h1 << 16);
                const float r3 = vr[3][dd] - from_hi(h1 & 0xFFFF0000u);
                *(uint2*)((char*)Vh + boff) = make_uint2(h0, h1);
                *(uint2*)((char*)Vl + boff) = make_uint2(pk_bf16(r0, r1), pk_bf16(r2, r3));
            }
        }
    };

    auto mfma_block = [&]() {
        const int kq = lane >> 4;
        const int mr = lane & 15;
        bf16x8_t ah[4], al_[4];
#pragma unroll
        for (int tm = 0; tm < 4; ++tm) {
            const int row  = wd + tm * 16 + mr;
            const int boff = row * (2 * RP) + ((kq * 16) ^ (((row >> 3) & 3) << 4));
            ah[tm]  = *(const bf16x8_t*)((const char*)Kh + boff);
            al_[tm] = *(const bf16x8_t*)((const char*)Kl + boff);
        }
        __builtin_amdgcn_s_setprio(1);
#pragma unroll
        for (int tn = 0; tn < 4; ++tn) {
            const int row  = wv + tn * 16 + mr;
            const int boff = row * (2 * RP) + ((kq * 16) ^ (((row >> 3) & 3) << 4));
            const bf16x8_t bh = *(const bf16x8_t*)((const char*)Vh + boff);
            const bf16x8_t bl = *(const bf16x8_t*)((const char*)Vl + boff);
#pragma unroll
            for (int tm = 0; tm < 4; ++tm) {
                acc[tm][tn] = __builtin_amdgcn_mfma_f32_16x16x32_bf16(ah[tm], bh, acc[tm][tn], 0, 0, 0);
                acc[tm][tn] = __builtin_amdgcn_mfma_f32_16x16x32_bf16(ah[tm], bl, acc[tm][tn], 0, 0, 0);
                acc[tm][tn] = __builtin_amdgcn_mfma_f32_16x16x32_bf16(al_[tm], bh, acc[tm][tn], 0, 0, 0);
            }
        }
        __builtin_amdgcn_s_setprio(0);
    };

    load_t(kA, vA, 0);
    load_t(kB, vB, 32);

    for (int t0 = 0; t0 < 512; t0 += 64) {
        // ---- half 1: consume A (tile t0) ----
        stage_t(kA, vA);                                    // compiler waits vmcnt(8): A done, B in flight
        asm volatile("s_waitcnt lgkmcnt(0)" ::: "memory");  // own ds_writes drained
        __builtin_amdgcn_s_barrier();
        __builtin_amdgcn_sched_barrier(0);
        if (t0 + 64 < 512) load_t(kA, vA, t0 + 64);         // refill A: flies across 2+ barriers
        __builtin_amdgcn_sched_barrier(0);
        mfma_block();
        asm volatile("s_waitcnt lgkmcnt(0)" ::: "memory");  // frag reads retired before overwrite
        __builtin_amdgcn_s_barrier();
        __builtin_amdgcn_sched_barrier(0);

        // ---- half 2: consume B (tile t0+32) ----
        stage_t(kB, vB);
        asm volatile("s_waitcnt lgkmcnt(0)" ::: "memory");
        __builtin_amdgcn_s_barrier();
        __builtin_amdgcn_sched_barrier(0);
        if (t0 + 96 < 512) load_t(kB, vB, t0 + 96);
        __builtin_amdgcn_sched_barrier(0);
        mfma_block();
        asm volatile("s_waitcnt lgkmcnt(0)" ::: "memory");
        __builtin_amdgcn_s_barrier();
        __builtin_amdgcn_sched_barrier(0);
    }

    // epilogue: fp32 partial (C/D layout: col=lane&15, row=quad*4+reg)
    float* Mp = Mpart + (size_t)(ts * 8 + b) * DD * DV;
    const int quad = lane >> 4;
    const int col  = lane & 15;
#pragma unroll
    for (int tm = 0; tm < 4; ++tm)
#pragma unroll
        for (int tn = 0; tn < 4; ++tn)
#pragma unroll
            for (int r = 0; r < 4; ++r) {
                const int d = d0 + wd + tm * 16 + quad * 4 + r;
                const int v = v0 + wv + tn * 16 + col;
                Mp[(size_t)d * DV + v] = acc[tm][tn][r];
            }
}

// ---------------------------------------------------------------------------
// Kernel 2: sum 4 partials, scale by 1/sqrt(512), transpose [d][v]->[v][d],
// emit Mt_hi/Mt_lo bf16 [b][v][d] into d_ws (8 MB total).  (unchanged)
// ---------------------------------------------------------------------------
__global__ __launch_bounds__(256) void reduce_cvt(const float* __restrict__ Mpart,
                                                  unsigned short* __restrict__ Mth,
                                                  unsigned short* __restrict__ Mtl) {
    const int b  = blockIdx.z;
    const int d0 = blockIdx.x * 64;
    const int v0 = blockIdx.y * 64;
    __shared__ float T[64][65];
    const int i  = threadIdx.x;
    const int xr = i >> 4;   // 0..15
    const int xc = i & 15;   // 0..15

#pragma unroll
    for (int e = 0; e < 4; ++e) {
        const int dr = e * 16 + xr;
        float sx = 0.f, sy = 0.f, sz = 0.f, sw = 0.f;
#pragma unroll
        for (int sl = 0; sl < 4; ++sl) {
            const float4 f = *(const float4*)&Mpart[((size_t)(sl * 8 + b) * DD + d0 + dr) * DV + v0 + xc * 4];
            sx += f.x; sy += f.y; sz += f.z; sw += f.w;
        }
        T[dr][xc * 4 + 0] = sx;
        T[dr][xc * 4 + 1] = sy;
        T[dr][xc * 4 + 2] = sz;
        T[dr][xc * 4 + 3] = sw;
    }
    __syncthreads();

    const float s = 0.04419417382415922f;  // 1/sqrt(512)
#pragma unroll
    for (int e = 0; e < 4; ++e) {
        const int v = e * 16 + xr;
        float m[4], r[4];
        unsigned int hv[2], lv[2];
#pragma unroll
        for (int j = 0; j < 4; ++j) m[j] = T[xc * 4 + j][v] * s;
#pragma unroll
        for (int j = 0; j < 2; ++j) {
            hv[j] = pk_bf16(m[2 * j], m[2 * j + 1]);
            r[2 * j]     = m[2 * j]     - from_hi(hv[j] << 16);
            r[2 * j + 1] = m[2 * j + 1] - from_hi(hv[j] & 0xFFFF0000u);
            lv[j] = pk_bf16(r[2 * j], r[2 * j + 1]);
        }
        const size_t o = ((size_t)b * DV + v0 + v) * DD + d0 + xc * 4;
        *(uint2*)&Mth[o] = make_uint2(hv[0], hv[1]);
        *(uint2*)&Mtl[o] = make_uint2(lv[0], lv[1]);
    }
}

// ---------------------------------------------------------------------------
// Kernel 3: X[b] = Q[b] @ M[b] via 3-term split MFMA. Same raw-barrier
// distance-2 pipeline as ktv. Staging pattern (already vectorized) kept.
// ---------------------------------------------------------------------------
__global__ __launch_bounds__(256) void qm_mfma(const float* __restrict__ Qp,
                                               const unsigned short* __restrict__ Mth,
                                               const unsigned short* __restrict__ Mtl,
                                               float* __restrict__ Xp) {
    const int b  = blockIdx.z;
    const int q0 = blockIdx.x * 128;
    const int v0 = blockIdx.y * 128;
    const float* Qb = Qp + (size_t)b * SQ * DD;
    const unsigned short* Bhg = Mth + (size_t)b * DV * DD;
    const unsigned short* Blg = Mtl + (size_t)b * DV * DD;

    __shared__ __align__(16) unsigned short Qh[128 * RP], Ql[128 * RP],
                                            Bh[128 * RP], Bl[128 * RP];

    const int tid  = threadIdx.x;
    const int lane = tid & 63;
    const int w    = tid >> 6;
    const int wq   = (w & 1) * 64;
    const int wv   = (w >> 1) * 64;

    f32x4_t acc[4][4];
#pragma unroll
    for (int i = 0; i < 4; ++i)
#pragma unroll
        for (int j = 0; j < 4; ++j) acc[i][j] = (f32x4_t){0.f, 0.f, 0.f, 0.f};

    const int qrow = tid >> 3;          // 0..31
    const int qdc  = (tid & 7) * 4;     // 0..28
    const int brow = tid >> 2;          // 0..63
    const int bkq  = tid & 3;           // 0..3

    // distance-2 prefetch buffers
    f32x4_t  qA[4], qB[4];
    bf16x8_t bhA[2], blA[2], bhB[2], blB[2];

    auto load_q = [&](f32x4_t* pq, bf16x8_t* pbh, bf16x8_t* pbl, int k0l) {
#pragma unroll
        for (int p = 0; p < 4; ++p)
            pq[p] = *(const f32x4_t*)&Qb[(size_t)(q0 + p * 32 + qrow) * DD + k0l + qdc];
#pragma unroll
        for (int p = 0; p < 2; ++p) {
            const size_t go = (size_t)(v0 + p * 64 + brow) * DD + k0l + bkq * 8;
            pbh[p] = *(const bf16x8_t*)&Bhg[go];
            pbl[p] = *(const bf16x8_t*)&Blg[go];
        }
    };

    auto stage_q = [&](const f32x4_t* pq, const bf16x8_t* pbh, const bf16x8_t* pbl) {
#pragma unroll
        for (int p = 0; p < 4; ++p) {
            const f32x4_t f = pq[p];
            const unsigned int h01 = pk_bf16(f[0], f[1]);
            const unsigned int h23 = pk_bf16(f[2], f[3]);
            const float r0 = f[0] - from_hi(h01 << 16);
            const float r1 = f[1] - from_hi(h01 & 0xFFFF0000u);
            const float r2 = f[2] - from_hi(h23 << 16);
            const float r3 = f[3] - from_hi(h23 & 0xFFFF0000u);
            const int off = (p * 32 + qrow) * RP + qdc;
            *(uint2*)(Qh + off) = make_uint2(h01, h23);
            *(uint2*)(Ql + off) = make_uint2(pk_bf16(r0, r1), pk_bf16(r2, r3));
        }
#pragma unroll
        for (int p = 0; p < 2; ++p) {
            const int off = (p * 64 + brow) * RP + bkq * 8;
            *(bf16x8_t*)(Bh + off) = pbh[p];
            *(bf16x8_t*)(Bl + off) = pbl[p];
        }
    };

    auto mfma_block = [&]() {
        const int kq = lane >> 4;
        const int mr = lane & 15;
        bf16x8_t ah[4], al_[4];
#pragma unroll
        for (int tm = 0; tm < 4; ++tm) {
            const int off = (wq + tm * 16 + mr) * RP + kq * 8;
            ah[tm]  = *(const bf16x8_t*)(Qh + off);
            al_[tm] = *(const bf16x8_t*)(Ql + off);
        }
        __builtin_amdgcn_s_setprio(1);
#pragma unroll
        for (int tn = 0; tn < 4; ++tn) {
            const int off = (wv + tn * 16 + mr) * RP + kq * 8;
            const bf16x8_t bh = *(const bf16x8_t*)(Bh + off);
            const bf16x8_t bl = *(const bf16x8_t*)(Bl + off);
#pragma unroll
            for (int tm = 0; tm < 4; ++tm) {
                acc[tm][tn] = __builtin_amdgcn_mfma_f32_16x16x32_bf16(ah[tm], bh, acc[tm][tn], 0, 0, 0);
                acc[tm][tn] = __builtin_amdgcn_mfma_f32_16x16x32_bf16(ah[tm], bl, acc[tm][tn], 0, 0, 0);
                acc[tm][tn] = __builtin_amdgcn_mfma_f32_16x16x32_bf16(al_[tm], bh, acc[tm][tn], 0, 0, 0);
            }
        }
        __builtin_amdgcn_s_setprio(0);
    };

    load_q(qA, bhA, blA, 0);
    load_q(qB, bhB, blB, 32);

    for (int k0 = 0; k0 < DD; k0 += 64) {
        // ---- half 1 ----
        stage_q(qA, bhA, blA);
        asm volatile("s_waitcnt lgkmcnt(0)" ::: "memory");
        __builtin_amdgcn_s_barrier();
        __builtin_amdgcn_sched_barrier(0);
        if (k0 + 64 < DD) load_q(qA, bhA, blA, k0 + 64);
        __builtin_amdgcn_sched_barrier(0);
        mfma_block();
        asm volatile("s_waitcnt lgkmcnt(0)" ::: "memory");
        __builtin_amdgcn_s_barrier();
        __builtin_amdgcn_sched_barrier(0);

        // ---- half 2 ----
        stage_q(qB, bhB, blB);
        asm volatile("s_waitcnt lgkmcnt(0)" ::: "memory");
        __builtin_amdgcn_s_barrier();
        __builtin_amdgcn_sched_barrier(0);
        if (k0 + 96 < DD) load_q(qB, bhB, blB, k0 + 96);
        __builtin_amdgcn_sched_barrier(0);
        mfma_block();
        asm volatile("s_waitcnt lgkmcnt(0)" ::: "memory");
        __builtin_amdgcn_s_barrier();
        __builtin_amdgcn_sched_barrier(0);
    }

    float* Xb = Xp + (size_t)b * SQ * DV;
    const int quad = lane >> 4;
    const int col  = lane & 15;
#pragma unroll
    for (int tm = 0; tm < 4; ++tm)
#pragma unroll
        for (int tn = 0; tn < 4; ++tn)
#pragma unroll
            for (int r = 0; r < 4; ++r)
                Xb[(size_t)(q0 + wq + tm * 16 + quad * 4 + r) * DV + v0 + wv + tn * 16 + col] = acc[tm][tn][r];
}

// ---------------------------------------------------------------------------
// Kernel 4: in-place masked softmax over last dim (512). One wave per row.
// (unchanged)
// ---------------------------------------------------------------------------
__global__ __launch_bounds__(256) void softmax_kernel(float* __restrict__ X,
                                                      const int* __restrict__ vlen) {
    const int wave = threadIdx.x >> 6;
    const int lane = threadIdx.x & 63;
    const int row  = blockIdx.x * 4 + wave;
    const int q    = row & (SQ - 1);
    float* xr = X + (size_t)row * DV;
    const int vl = vlen[q];

    float v[8];
#pragma unroll
    for (int u = 0; u < 2; ++u) {
        const int j0 = u * 256 + lane * 4;
        const float4 f = *(const float4*)&xr[j0];
        v[u * 4 + 0] = (j0 + 0 > vl) ? -1.0e6f : f.x;
        v[u * 4 + 1] = (j0 + 1 > vl) ? -1.0e6f : f.y;
        v[u * 4 + 2] = (j0 + 2 > vl) ? -1.0e6f : f.z;
        v[u * 4 + 3] = (j0 + 3 > vl) ? -1.0e6f : f.w;
    }

    float m = v[0];
#pragma unroll
    for (int i = 1; i < 8; ++i) m = fmaxf(m, v[i]);
#pragma unroll
    for (int off = 32; off > 0; off >>= 1) m = fmaxf(m, __shfl_xor(m, off, 64));

    float ssum = 0.f;
#pragma unroll
    for (int i = 0; i < 8; ++i) {
        v[i] = __expf(v[i] - m);
        ssum += v[i];
    }
#pragma unroll
    for (int off = 32; off > 0; off >>= 1) ssum += __shfl_xor(ssum, off, 64);

    const float inv = 1.0f / ssum;
#pragma unroll
    for (int u = 0; u < 2; ++u) {
        const int j0 = u * 256 + lane * 4;
        float4 o;
        o.x = v[u * 4 + 0] * inv;
        o.y = v[u * 4 + 1] * inv;
        o.z = v[u * 4 + 2] * inv;
        o.w = v[u * 4 + 3] * inv;
        *(float4*)&xr[j0] = o;
    }
}

extern "C" void kernel_launch(void* const* d_in, const int* in_sizes, int n_in,
                              void* d_out, int out_size, void* d_ws, size_t ws_size,
                              hipStream_t stream) {
    const float* Kp   = (const float*)d_in[0];
    const float* Vp   = (const float*)d_in[1];
    const float* Qp   = (const float*)d_in[2];
    const int*   vlen = (const int*)d_in[3];
    float* out = (float*)d_out;

    // ws: Mt_hi (4 MB) | Mt_lo (4 MB) -- proven-safe 8 MB footprint.
    unsigned short* Mth = (unsigned short*)d_ws;
    unsigned short* Mtl = Mth + (size_t)BATCH * DD * DV;
    // fp32 partials (4 x 8 MB = 32 MB) live in d_out; overwritten by qm later.
    float* Mpart = out;

    ktv_mfma<<<dim3(4, 4, 32), 256, 0, stream>>>(Kp, Vp, Mpart);
    reduce_cvt<<<dim3(8, 8, 8), 256, 0, stream>>>(Mpart, Mth, Mtl);
    qm_mfma<<<dim3(16, 4, 8), 256, 0, stream>>>(Qp, Mth, Mtl, out);
    softmax_kernel<<<dim3(BATCH * SQ / 4), 256, 0, stream>>>(out, vlen);
}

// Round 2
// 234.811 us; speedup vs baseline: 1.0322x; 1.0322x over previous
//
#include <hip/hip_runtime.h>
#include <hip/hip_bf16.h>
#include <math.h>

#define BATCH 8
#define SQ 2048
#define SK 2048
#define DD 512
#define DV 512
#define RP 40   // LDS row pitch in shorts (80 B). Frag b128 reads are 2-way (free, m136);
                // the 2^23 SQ_LDS_BANK_CONFLICT floor is structural -- do not chase.

typedef short bf16x8_t __attribute__((ext_vector_type(8)));
typedef float f32x4_t __attribute__((ext_vector_type(4)));
typedef unsigned int u32x4_t __attribute__((ext_vector_type(4)));

// packed RTNE fp32x2 -> bf16x2 (v_cvt_pk_bf16_f32)
__device__ __forceinline__ unsigned int pk_bf16(float a, float b) {
    __hip_bfloat162 h = __float22bfloat162_rn(float2{a, b});
    unsigned int u;
    __builtin_memcpy(&u, &h, 4);
    return u;
}
__device__ __forceinline__ float from_hi(unsigned int u) {
    return __builtin_bit_cast(float, u);
}

// split 8 consecutive fp32 (two f32x4) into bf16x8 hi + bf16x8 lo, bit-identical
// to the LDS staging path (same pk_bf16 ops, same order).
__device__ __forceinline__ void cvt_split8(const f32x4_t a, const f32x4_t b,
                                           bf16x8_t& hi, bf16x8_t& lo) {
    const unsigned int h0 = pk_bf16(a[0], a[1]);
    const unsigned int h1 = pk_bf16(a[2], a[3]);
    const unsigned int h2 = pk_bf16(b[0], b[1]);
    const unsigned int h3 = pk_bf16(b[2], b[3]);
    const float r0 = a[0] - from_hi(h0 << 16);
    const float r1 = a[1] - from_hi(h0 & 0xFFFF0000u);
    const float r2 = a[2] - from_hi(h1 << 16);
    const float r3 = a[3] - from_hi(h1 & 0xFFFF0000u);
    const float r4 = b[0] - from_hi(h2 << 16);
    const float r5 = b[1] - from_hi(h2 & 0xFFFF0000u);
    const float r6 = b[2] - from_hi(h3 << 16);
    const float r7 = b[3] - from_hi(h3 & 0xFFFF0000u);
    const u32x4_t hv = {h0, h1, h2, h3};
    const u32x4_t lv = {pk_bf16(r0, r1), pk_bf16(r2, r3), pk_bf16(r4, r5), pk_bf16(r6, r7)};
    hi = __builtin_bit_cast(bf16x8_t, hv);
    lo = __builtin_bit_cast(bf16x8_t, lv);
}

// ---------------------------------------------------------------------------
// Kernel 1: fp32 partials of K^T V (un-scaled), t-split by 4.
// Mpart: [ts(4)][b(8)][d(512)][v(512)] fp32 == 32 MB, lives in d_out.
// 128x128 tile, BK=32, register-prefetch pipeline (round-0 known-good form).
// 3-term split MFMA: Kh*Vh + Kh*Vl + Kl*Vh.
// ---------------------------------------------------------------------------
__global__ __launch_bounds__(256) void ktv_mfma(const float* __restrict__ Kp,
                                                const float* __restrict__ Vp,
                                                float* __restrict__ Mpart) {
    const int b  = blockIdx.z & 7;
    const int ts = blockIdx.z >> 3;
    const int d0 = blockIdx.x * 128;
    const int v0 = blockIdx.y * 128;
    const float* Kb = Kp + (size_t)b * SK * DD;
    const float* Vb = Vp + (size_t)b * SK * DV;

    __shared__ __align__(16) unsigned short Kh[128 * RP], Kl[128 * RP],
                                            Vh[128 * RP], Vl[128 * RP];

    const int tid  = threadIdx.x;
    const int lane = tid & 63;
    const int w    = tid >> 6;
    const int wd   = (w & 1) * 64;
    const int wv   = (w >> 1) * 64;
    const int uu   = tid >> 5;   // 0..7  (t-pair selector)
    const int xx   = tid & 31;   // d/v column selector

    f32x4_t acc[4][4];
#pragma unroll
    for (int i = 0; i < 4; ++i)
#pragma unroll
        for (int j = 0; j < 4; ++j) acc[i][j] = (f32x4_t){0.f, 0.f, 0.f, 0.f};

    const int tb = ts * 512;

    // prefetch registers: K and V, (p,c) x {t, t+1}
    float kr0[2][4], kr1[2][4], vr0[2][4], vr1[2][4];
    auto load_tile = [&](int t0l) {
#pragma unroll
        for (int p = 0; p < 2; ++p) {
            const int t = 16 * p + 2 * uu;
            const size_t gr = (size_t)(tb + t0l + t);
#pragma unroll
            for (int c = 0; c < 4; ++c) {
                const int d = xx + 32 * c;
                kr0[p][c] = Kb[gr * DD + d0 + d];
                kr1[p][c] = Kb[(gr + 1) * DD + d0 + d];
                vr0[p][c] = Vb[gr * DV + v0 + d];
                vr1[p][c] = Vb[(gr + 1) * DV + v0 + d];
            }
        }
    };

    load_tile(0);
    for (int t0 = 0; t0 < 512; t0 += 32) {
        // ---- cvt + LDS store from prefetched regs ----
#pragma unroll
        for (int p = 0; p < 2; ++p) {
            const int t  = 16 * p + 2 * uu;
            const int to = (t >> 3) * 8 + (t & 7);
#pragma unroll
            for (int c = 0; c < 4; ++c) {
                const int d   = xx + 32 * c;
                const int off = d * RP + to;
                {
                    const unsigned int h = pk_bf16(kr0[p][c], kr1[p][c]);
                    const float r0 = kr0[p][c] - from_hi(h << 16);
                    const float r1 = kr1[p][c] - from_hi(h & 0xFFFF0000u);
                    *(unsigned int*)(Kh + off) = h;
                    *(unsigned int*)(Kl + off) = pk_bf16(r0, r1);
                }
                {
                    const unsigned int h = pk_bf16(vr0[p][c], vr1[p][c]);
                    const float r0 = vr0[p][c] - from_hi(h << 16);
                    const float r1 = vr1[p][c] - from_hi(h & 0xFFFF0000u);
                    *(unsigned int*)(Vh + off) = h;
                    *(unsigned int*)(Vl + off) = pk_bf16(r0, r1);
                }
            }
        }
        __syncthreads();

        // issue next tile's loads now -- they overlap the MFMA block below
        if (t0 + 32 < 512) load_tile(t0 + 32);

        // ---- MFMA ----
        const int kq = lane >> 4;
        const int mr = lane & 15;
        bf16x8_t ah[4], al_[4];
#pragma unroll
        for (int tm = 0; tm < 4; ++tm) {
            const int off = (wd + tm * 16 + mr) * RP + kq * 8;
            ah[tm]  = *(const bf16x8_t*)(Kh + off);
            al_[tm] = *(const bf16x8_t*)(Kl + off);
        }
#pragma unroll
        for (int tn = 0; tn < 4; ++tn) {
            const int off = (wv + tn * 16 + mr) * RP + kq * 8;
            const bf16x8_t bh = *(const bf16x8_t*)(Vh + off);
            const bf16x8_t bl = *(const bf16x8_t*)(Vl + off);
#pragma unroll
            for (int tm = 0; tm < 4; ++tm) {
                acc[tm][tn] = __builtin_amdgcn_mfma_f32_16x16x32_bf16(ah[tm], bh, acc[tm][tn], 0, 0, 0);
                acc[tm][tn] = __builtin_amdgcn_mfma_f32_16x16x32_bf16(ah[tm], bl, acc[tm][tn], 0, 0, 0);
                acc[tm][tn] = __builtin_amdgcn_mfma_f32_16x16x32_bf16(al_[tm], bh, acc[tm][tn], 0, 0, 0);
            }
        }
        __syncthreads();
    }

    // epilogue: fp32 partial (C/D layout: col=lane&15, row=quad*4+reg)
    float* Mp = Mpart + (size_t)(ts * 8 + b) * DD * DV;
    const int quad = lane >> 4;
    const int col  = lane & 15;
#pragma unroll
    for (int tm = 0; tm < 4; ++tm)
#pragma unroll
        for (int tn = 0; tn < 4; ++tn)
#pragma unroll
            for (int r = 0; r < 4; ++r) {
                const int d = d0 + wd + tm * 16 + quad * 4 + r;
                const int v = v0 + wv + tn * 16 + col;
                Mp[(size_t)d * DV + v] = acc[tm][tn][r];
            }
}

// ---------------------------------------------------------------------------
// Kernel 2: sum 4 partials, scale by 1/sqrt(512), transpose [d][v]->[v][d],
// emit Mt_hi/Mt_lo bf16 [b][v][d] into d_ws (8 MB total).  (round-0 form)
// ---------------------------------------------------------------------------
__global__ __launch_bounds__(256) void reduce_cvt(const float* __restrict__ Mpart,
                                                  unsigned short* __restrict__ Mth,
                                                  unsigned short* __restrict__ Mtl) {
    const int b  = blockIdx.z;
    const int d0 = blockIdx.x * 64;
    const int v0 = blockIdx.y * 64;
    __shared__ float T[64][65];
    const int i  = threadIdx.x;
    const int xr = i >> 4;   // 0..15
    const int xc = i & 15;   // 0..15

#pragma unroll
    for (int e = 0; e < 4; ++e) {
        const int dr = e * 16 + xr;
        float sx = 0.f, sy = 0.f, sz = 0.f, sw = 0.f;
#pragma unroll
        for (int sl = 0; sl < 4; ++sl) {
            const float4 f = *(const float4*)&Mpart[((size_t)(sl * 8 + b) * DD + d0 + dr) * DV + v0 + xc * 4];
            sx += f.x; sy += f.y; sz += f.z; sw += f.w;
        }
        T[dr][xc * 4 + 0] = sx;
        T[dr][xc * 4 + 1] = sy;
        T[dr][xc * 4 + 2] = sz;
        T[dr][xc * 4 + 3] = sw;
    }
    __syncthreads();

    const float s = 0.04419417382415922f;  // 1/sqrt(512)
#pragma unroll
    for (int e = 0; e < 4; ++e) {
        const int v = e * 16 + xr;
        float m[4], r[4];
        unsigned int hv[2], lv[2];
#pragma unroll
        for (int j = 0; j < 4; ++j) m[j] = T[xc * 4 + j][v] * s;
#pragma unroll
        for (int j = 0; j < 2; ++j) {
            hv[j] = pk_bf16(m[2 * j], m[2 * j + 1]);
            r[2 * j]     = m[2 * j]     - from_hi(hv[j] << 16);
            r[2 * j + 1] = m[2 * j + 1] - from_hi(hv[j] & 0xFFFF0000u);
            lv[j] = pk_bf16(r[2 * j], r[2 * j + 1]);
        }
        const size_t o = ((size_t)b * DV + v0 + v) * DD + d0 + xc * 4;
        *(uint2*)&Mth[o] = make_uint2(hv[0], hv[1]);
        *(uint2*)&Mtl[o] = make_uint2(lv[0], lv[1]);
    }
}

// ---------------------------------------------------------------------------
// Kernel 3: X[b] = Q[b] @ M[b] via 3-term split MFMA.
// NEW: zero LDS, zero barriers. B (Mth/Mtl, 8 MB total) is k-contiguous
// [v][d] in global -- exactly the B-frag access pattern -- and L2/L3-resident
// (Common-mistake #7: don't LDS-stage cache-fit data). Q frags are 8
// consecutive fp32 of one q-row; hi/lo split done in-register (bit-identical
// to the old LDS path). Distance-1 register double-buffer (named sets) hides
// L2/L3 latency under the 48-MFMA body; waves run fully independent.
// ---------------------------------------------------------------------------
__global__ __launch_bounds__(256, 2) void qm_mfma(const float* __restrict__ Qp,
                                                  const unsigned short* __restrict__ Mth,
                                                  const unsigned short* __restrict__ Mtl,
                                                  float* __restrict__ Xp) {
    const int b  = blockIdx.z;
    const int q0 = blockIdx.x * 128;
    const int v0 = blockIdx.y * 128;
    const float* Qb = Qp + (size_t)b * SQ * DD;
    const unsigned short* Bhg = Mth + (size_t)b * DV * DD;
    const unsigned short* Blg = Mtl + (size_t)b * DV * DD;

    const int tid  = threadIdx.x;
    const int lane = tid & 63;
    const int w    = tid >> 6;
    const int wq   = (w & 1) * 64;
    const int wv   = (w >> 1) * 64;
    const int kq   = lane >> 4;   // 0..3  k-chunk (8 elements each)
    const int mr   = lane & 15;   // row within 16

    f32x4_t acc[4][4];
#pragma unroll
    for (int i = 0; i < 4; ++i)
#pragma unroll
        for (int j = 0; j < 4; ++j) acc[i][j] = (f32x4_t){0.f, 0.f, 0.f, 0.f};

    // per-lane base pointers (frag layout == global layout, k-contiguous)
    const float* qptr[4];
    size_t boff[4];
#pragma unroll
    for (int tm = 0; tm < 4; ++tm)
        qptr[tm] = Qb + (size_t)(q0 + wq + tm * 16 + mr) * DD + kq * 8;
#pragma unroll
    for (int tn = 0; tn < 4; ++tn)
        boff[tn] = (size_t)(v0 + wv + tn * 16 + mr) * DD + kq * 8;

    // distance-1 prefetch: two named register sets (rule #20: static indexing)
    f32x4_t  qrA[4][2], qrB[4][2];
    bf16x8_t bhA[4], blA[4], bhB[4], blB[4];

    auto loadQ = [&](f32x4_t (*qr)[2], int k) {
#pragma unroll
        for (int tm = 0; tm < 4; ++tm) {
            qr[tm][0] = *(const f32x4_t*)(qptr[tm] + k);
            qr[tm][1] = *(const f32x4_t*)(qptr[tm] + k + 4);
        }
    };
    auto loadB = [&](bf16x8_t* bh, bf16x8_t* bl, int k) {
#pragma unroll
        for (int tn = 0; tn < 4; ++tn) {
            bh[tn] = *(const bf16x8_t*)&Bhg[boff[tn] + k];
            bl[tn] = *(const bf16x8_t*)&Blg[boff[tn] + k];
        }
    };
    auto body = [&](f32x4_t (*qr)[2], const bf16x8_t* bh, const bf16x8_t* bl) {
        bf16x8_t ah[4], al_[4];
#pragma unroll
        for (int tm = 0; tm < 4; ++tm)
            cvt_split8(qr[tm][0], qr[tm][1], ah[tm], al_[tm]);
#pragma unroll
        for (int tn = 0; tn < 4; ++tn)
#pragma unroll
            for (int tm = 0; tm < 4; ++tm) {
                acc[tm][tn] = __builtin_amdgcn_mfma_f32_16x16x32_bf16(ah[tm], bh[tn], acc[tm][tn], 0, 0, 0);
                acc[tm][tn] = __builtin_amdgcn_mfma_f32_16x16x32_bf16(ah[tm], bl[tn], acc[tm][tn], 0, 0, 0);
                acc[tm][tn] = __builtin_amdgcn_mfma_f32_16x16x32_bf16(al_[tm], bh[tn], acc[tm][tn], 0, 0, 0);
            }
    };

    loadQ(qrA, 0);
    loadB(bhA, blA, 0);
    for (int k0 = 0; k0 < DD; k0 += 64) {
        if (k0 + 32 < DD) { loadQ(qrB, k0 + 32); loadB(bhB, blB, k0 + 32); }
        body(qrA, bhA, blA);
        if (k0 + 64 < DD) { loadQ(qrA, k0 + 64); loadB(bhA, blA, k0 + 64); }
        body(qrB, bhB, blB);
    }

    float* Xb = Xp + (size_t)b * SQ * DV;
    const int quad = lane >> 4;
    const int col  = lane & 15;
#pragma unroll
    for (int tm = 0; tm < 4; ++tm)
#pragma unroll
        for (int tn = 0; tn < 4; ++tn)
#pragma unroll
            for (int r = 0; r < 4; ++r)
                Xb[(size_t)(q0 + wq + tm * 16 + quad * 4 + r) * DV + v0 + wv + tn * 16 + col] = acc[tm][tn][r];
}

// ---------------------------------------------------------------------------
// Kernel 4: in-place masked softmax over last dim (512). One wave per row.
// ---------------------------------------------------------------------------
__global__ __launch_bounds__(256) void softmax_kernel(float* __restrict__ X,
                                                      const int* __restrict__ vlen) {
    const int wave = threadIdx.x >> 6;
    const int lane = threadIdx.x & 63;
    const int row  = blockIdx.x * 4 + wave;
    const int q    = row & (SQ - 1);
    float* xr = X + (size_t)row * DV;
    const int vl = vlen[q];

    float v[8];
#pragma unroll
    for (int u = 0; u < 2; ++u) {
        const int j0 = u * 256 + lane * 4;
        const float4 f = *(const float4*)&xr[j0];
        v[u * 4 + 0] = (j0 + 0 > vl) ? -1.0e6f : f.x;
        v[u * 4 + 1] = (j0 + 1 > vl) ? -1.0e6f : f.y;
        v[u * 4 + 2] = (j0 + 2 > vl) ? -1.0e6f : f.z;
        v[u * 4 + 3] = (j0 + 3 > vl) ? -1.0e6f : f.w;
    }

    float m = v[0];
#pragma unroll
    for (int i = 1; i < 8; ++i) m = fmaxf(m, v[i]);
#pragma unroll
    for (int off = 32; off > 0; off >>= 1) m = fmaxf(m, __shfl_xor(m, off, 64));

    float ssum = 0.f;
#pragma unroll
    for (int i = 0; i < 8; ++i) {
        v[i] = __expf(v[i] - m);
        ssum += v[i];
    }
#pragma unroll
    for (int off = 32; off > 0; off >>= 1) ssum += __shfl_xor(ssum, off, 64);

    const float inv = 1.0f / ssum;
#pragma unroll
    for (int u = 0; u < 2; ++u) {
        const int j0 = u * 256 + lane * 4;
        float4 o;
        o.x = v[u * 4 + 0] * inv;
        o.y = v[u * 4 + 1] * inv;
        o.z = v[u * 4 + 2] * inv;
        o.w = v[u * 4 + 3] * inv;
        *(float4*)&xr[j0] = o;
    }
}

extern "C" void kernel_launch(void* const* d_in, const int* in_sizes, int n_in,
                              void* d_out, int out_size, void* d_ws, size_t ws_size,
                              hipStream_t stream) {
    const float* Kp   = (const float*)d_in[0];
    const float* Vp   = (const float*)d_in[1];
    const float* Qp   = (const float*)d_in[2];
    const int*   vlen = (const int*)d_in[3];
    float* out = (float*)d_out;

    // ws: Mt_hi (4 MB) | Mt_lo (4 MB) -- proven-safe 8 MB footprint.
    unsigned short* Mth = (unsigned short*)d_ws;
    unsigned short* Mtl = Mth + (size_t)BATCH * DD * DV;
    // fp32 partials (4 x 8 MB = 32 MB) live in d_out; overwritten by qm later.
    float* Mpart = out;

    ktv_mfma<<<dim3(4, 4, 32), 256, 0, stream>>>(Kp, Vp, Mpart);
    reduce_cvt<<<dim3(8, 8, 8), 256, 0, stream>>>(Mpart, Mth, Mtl);
    qm_mfma<<<dim3(16, 4, 8), 256, 0, stream>>>(Qp, Mth, Mtl, out);
    softmax_kernel<<<dim3(BATCH * SQ / 4), 256, 0, stream>>>(out, vlen);
}

// Round 3
// 194.828 us; speedup vs baseline: 1.2441x; 1.2052x over previous
//
#include <hip/hip_runtime.h>
#include <hip/hip_bf16.h>
#include <math.h>

#define BATCH 8
#define SQ 2048
#define SK 2048
#define DD 512
#define DV 512
#define RP 40   // LDS row pitch in shorts (80 B). Frag b128 reads are 2-way (free, m136);
                // the 2^23 SQ_LDS_BANK_CONFLICT floor is structural -- do not chase.

typedef short bf16x8_t __attribute__((ext_vector_type(8)));
typedef float f32x4_t __attribute__((ext_vector_type(4)));

// packed RTNE fp32x2 -> bf16x2 (v_cvt_pk_bf16_f32)
__device__ __forceinline__ unsigned int pk_bf16(float a, float b) {
    __hip_bfloat162 h = __float22bfloat162_rn(float2{a, b});
    unsigned int u;
    __builtin_memcpy(&u, &h, 4);
    return u;
}
__device__ __forceinline__ float from_hi(unsigned int u) {
    return __builtin_bit_cast(float, u);
}

// ---------------------------------------------------------------------------
// Kernel 1: fp32 partials of M^T = V^T K (un-scaled), t-split by 4.
// SWAPPED OPERANDS vs round-0: A-frags from V, B-frags from K, so the
// accumulator tile is [v][d] directly -- no transpose needed downstream.
// Mpart: [ts(4)][b(8)][v(512)][d(512)] fp32 == 32 MB, lives in d_out.
// Staging, LDS layout, pipeline identical to the round-0 known-good form.
// 3-term split MFMA: Vh*Kh + Vh*Kl + Vl*Kh (same products as before).
// ---------------------------------------------------------------------------
__global__ __launch_bounds__(256) void ktv_mfma(const float* __restrict__ Kp,
                                                const float* __restrict__ Vp,
                                                float* __restrict__ Mpart) {
    const int b  = blockIdx.z & 7;
    const int ts = blockIdx.z >> 3;
    const int d0 = blockIdx.x * 128;
    const int v0 = blockIdx.y * 128;
    const float* Kb = Kp + (size_t)b * SK * DD;
    const float* Vb = Vp + (size_t)b * SK * DV;

    __shared__ __align__(16) unsigned short Kh[128 * RP], Kl[128 * RP],
                                            Vh[128 * RP], Vl[128 * RP];

    const int tid  = threadIdx.x;
    const int lane = tid & 63;
    const int w    = tid >> 6;
    const int wv   = (w & 1) * 64;    // A-side: v rows
    const int wd   = (w >> 1) * 64;   // B-side: d rows
    const int uu   = tid >> 5;   // 0..7  (t-pair selector)
    const int xx   = tid & 31;   // d/v column selector

    f32x4_t acc[4][4];
#pragma unroll
    for (int i = 0; i < 4; ++i)
#pragma unroll
        for (int j = 0; j < 4; ++j) acc[i][j] = (f32x4_t){0.f, 0.f, 0.f, 0.f};

    const int tb = ts * 512;

    // prefetch registers: K and V, (p,c) x {t, t+1}
    float kr0[2][4], kr1[2][4], vr0[2][4], vr1[2][4];
    auto load_tile = [&](int t0l) {
#pragma unroll
        for (int p = 0; p < 2; ++p) {
            const int t = 16 * p + 2 * uu;
            const size_t gr = (size_t)(tb + t0l + t);
#pragma unroll
            for (int c = 0; c < 4; ++c) {
                const int d = xx + 32 * c;
                kr0[p][c] = Kb[gr * DD + d0 + d];
                kr1[p][c] = Kb[(gr + 1) * DD + d0 + d];
                vr0[p][c] = Vb[gr * DV + v0 + d];
                vr1[p][c] = Vb[(gr + 1) * DV + v0 + d];
            }
        }
    };

    load_tile(0);
    for (int t0 = 0; t0 < 512; t0 += 32) {
        // ---- cvt + LDS store from prefetched regs ----
#pragma unroll
        for (int p = 0; p < 2; ++p) {
            const int t  = 16 * p + 2 * uu;
            const int to = (t >> 3) * 8 + (t & 7);
#pragma unroll
            for (int c = 0; c < 4; ++c) {
                const int d   = xx + 32 * c;
                const int off = d * RP + to;
                {
                    const unsigned int h = pk_bf16(kr0[p][c], kr1[p][c]);
                    const float r0 = kr0[p][c] - from_hi(h << 16);
                    const float r1 = kr1[p][c] - from_hi(h & 0xFFFF0000u);
                    *(unsigned int*)(Kh + off) = h;
                    *(unsigned int*)(Kl + off) = pk_bf16(r0, r1);
                }
                {
                    const unsigned int h = pk_bf16(vr0[p][c], vr1[p][c]);
                    const float r0 = vr0[p][c] - from_hi(h << 16);
                    const float r1 = vr1[p][c] - from_hi(h & 0xFFFF0000u);
                    *(unsigned int*)(Vh + off) = h;
                    *(unsigned int*)(Vl + off) = pk_bf16(r0, r1);
                }
            }
        }
        __syncthreads();

        // issue next tile's loads now -- they overlap the MFMA block below
        if (t0 + 32 < 512) load_tile(t0 + 32);

        // ---- MFMA (A = V rows, B = K rows) ----
        const int kq = lane >> 4;
        const int mr = lane & 15;
        bf16x8_t ah[4], al_[4];
#pragma unroll
        for (int tm = 0; tm < 4; ++tm) {
            const int off = (wv + tm * 16 + mr) * RP + kq * 8;
            ah[tm]  = *(const bf16x8_t*)(Vh + off);
            al_[tm] = *(const bf16x8_t*)(Vl + off);
        }
#pragma unroll
        for (int tn = 0; tn < 4; ++tn) {
            const int off = (wd + tn * 16 + mr) * RP + kq * 8;
            const bf16x8_t bh = *(const bf16x8_t*)(Kh + off);
            const bf16x8_t bl = *(const bf16x8_t*)(Kl + off);
#pragma unroll
            for (int tm = 0; tm < 4; ++tm) {
                acc[tm][tn] = __builtin_amdgcn_mfma_f32_16x16x32_bf16(ah[tm], bh, acc[tm][tn], 0, 0, 0);
                acc[tm][tn] = __builtin_amdgcn_mfma_f32_16x16x32_bf16(ah[tm], bl, acc[tm][tn], 0, 0, 0);
                acc[tm][tn] = __builtin_amdgcn_mfma_f32_16x16x32_bf16(al_[tm], bh, acc[tm][tn], 0, 0, 0);
            }
        }
        __syncthreads();
    }

    // epilogue: fp32 partial, [v][d] layout (C/D: col=lane&15, row=quad*4+reg)
    float* Mp = Mpart + (size_t)(ts * 8 + b) * DV * DD;
    const int quad = lane >> 4;
    const int col  = lane & 15;
#pragma unroll
    for (int tm = 0; tm < 4; ++tm)
#pragma unroll
        for (int tn = 0; tn < 4; ++tn)
#pragma unroll
            for (int r = 0; r < 4; ++r) {
                const int v = v0 + wv + tm * 16 + quad * 4 + r;  // A-side row
                const int d = d0 + wd + tn * 16 + col;           // B-side col
                Mp[(size_t)v * DD + d] = acc[tm][tn][r];
            }
}

// ---------------------------------------------------------------------------
// Kernel 2: pure streaming reduce -- partials are already [v][d], so no
// transpose, no LDS, no barriers. Sum 4 slices, scale by 1/sqrt(512),
// split bf16 hi/lo, write Mth/Mtl [b][v][d]. 40 MB traffic, fully coalesced.
// ---------------------------------------------------------------------------
__global__ __launch_bounds__(256) void reduce_cvt(const float* __restrict__ Mpart,
                                                  unsigned short* __restrict__ Mth,
                                                  unsigned short* __restrict__ Mtl) {
    const size_t N  = (size_t)BATCH * DD * DV;                    // floats per slice
    const size_t i4 = ((size_t)blockIdx.x * 256 + threadIdx.x) * 4;

    float sx = 0.f, sy = 0.f, sz = 0.f, sw = 0.f;
#pragma unroll
    for (int sl = 0; sl < 4; ++sl) {
        const float4 f = *(const float4*)&Mpart[sl * N + i4];
        sx += f.x; sy += f.y; sz += f.z; sw += f.w;
    }

    const float s = 0.04419417382415922f;  // 1/sqrt(512)
    const float m0 = sx * s, m1 = sy * s, m2 = sz * s, m3 = sw * s;
    const unsigned int h0 = pk_bf16(m0, m1);
    const unsigned int h1 = pk_bf16(m2, m3);
    const float r0 = m0 - from_hi(h0 << 16);
    const float r1 = m1 - from_hi(h0 & 0xFFFF0000u);
    const float r2 = m2 - from_hi(h1 << 16);
    const float r3 = m3 - from_hi(h1 & 0xFFFF0000u);
    *(uint2*)&Mth[i4] = make_uint2(h0, h1);
    *(uint2*)&Mtl[i4] = make_uint2(pk_bf16(r0, r1), pk_bf16(r2, r3));
}

// ---------------------------------------------------------------------------
// Kernel 3: X[b] = Q[b] @ M[b] via 3-term split MFMA. B pre-split bf16
// k-contiguous from ws; Q converted on the fly. 128x128 tiles, BK=32,
// register-prefetch pipeline. (round-0 known-good form, verbatim)
// ---------------------------------------------------------------------------
__global__ __launch_bounds__(256) void qm_mfma(const float* __restrict__ Qp,
                                               const unsigned short* __restrict__ Mth,
                                               const unsigned short* __restrict__ Mtl,
                                               float* __restrict__ Xp) {
    const int b  = blockIdx.z;
    const int q0 = blockIdx.x * 128;
    const int v0 = blockIdx.y * 128;
    const float* Qb = Qp + (size_t)b * SQ * DD;
    const unsigned short* Bhg = Mth + (size_t)b * DV * DD;
    const unsigned short* Blg = Mtl + (size_t)b * DV * DD;

    __shared__ __align__(16) unsigned short Qh[128 * RP], Ql[128 * RP],
                                            Bh[128 * RP], Bl[128 * RP];

    const int tid  = threadIdx.x;
    const int lane = tid & 63;
    const int w    = tid >> 6;
    const int wq   = (w & 1) * 64;
    const int wv   = (w >> 1) * 64;

    f32x4_t acc[4][4];
#pragma unroll
    for (int i = 0; i < 4; ++i)
#pragma unroll
        for (int j = 0; j < 4; ++j) acc[i][j] = (f32x4_t){0.f, 0.f, 0.f, 0.f};

    // prefetch registers
    float4 pq[4];
    bf16x8_t pbh[2], pbl[2];
    const int qrow = tid >> 3;          // 0..31
    const int qdc  = (tid & 7) * 4;     // 0..28
    const int brow = tid >> 2;          // 0..63
    const int bkq  = tid & 3;           // 0..3
    auto load_tile = [&](int k0l) {
#pragma unroll
        for (int p = 0; p < 4; ++p)
            pq[p] = *(const float4*)&Qb[(size_t)(q0 + p * 32 + qrow) * DD + k0l + qdc];
#pragma unroll
        for (int p = 0; p < 2; ++p) {
            const size_t go = (size_t)(v0 + p * 64 + brow) * DD + k0l + bkq * 8;
            pbh[p] = *(const bf16x8_t*)&Bhg[go];
            pbl[p] = *(const bf16x8_t*)&Blg[go];
        }
    };

    load_tile(0);
    for (int k0 = 0; k0 < DD; k0 += 32) {
        // ---- stage Q (cvt+split) and B (straight copy) from regs ----
#pragma unroll
        for (int p = 0; p < 4; ++p) {
            const float4 f = pq[p];
            const unsigned int h01 = pk_bf16(f.x, f.y);
            const unsigned int h23 = pk_bf16(f.z, f.w);
            const float r0 = f.x - from_hi(h01 << 16);
            const float r1 = f.y - from_hi(h01 & 0xFFFF0000u);
            const float r2 = f.z - from_hi(h23 << 16);
            const float r3 = f.w - from_hi(h23 & 0xFFFF0000u);
            const int off = (p * 32 + qrow) * RP + qdc;
            *(uint2*)(Qh + off) = make_uint2(h01, h23);
            *(uint2*)(Ql + off) = make_uint2(pk_bf16(r0, r1), pk_bf16(r2, r3));
        }
#pragma unroll
        for (int p = 0; p < 2; ++p) {
            const int off = (p * 64 + brow) * RP + bkq * 8;
            *(bf16x8_t*)(Bh + off) = pbh[p];
            *(bf16x8_t*)(Bl + off) = pbl[p];
        }
        __syncthreads();

        if (k0 + 32 < DD) load_tile(k0 + 32);

        const int kq = lane >> 4;
        const int mr = lane & 15;
        bf16x8_t ah[4], al_[4];
#pragma unroll
        for (int tm = 0; tm < 4; ++tm) {
            const int off = (wq + tm * 16 + mr) * RP + kq * 8;
            ah[tm]  = *(const bf16x8_t*)(Qh + off);
            al_[tm] = *(const bf16x8_t*)(Ql + off);
        }
#pragma unroll
        for (int tn = 0; tn < 4; ++tn) {
            const int off = (wv + tn * 16 + mr) * RP + kq * 8;
            const bf16x8_t bh = *(const bf16x8_t*)(Bh + off);
            const bf16x8_t bl = *(const bf16x8_t*)(Bl + off);
#pragma unroll
            for (int tm = 0; tm < 4; ++tm) {
                acc[tm][tn] = __builtin_amdgcn_mfma_f32_16x16x32_bf16(ah[tm], bh, acc[tm][tn], 0, 0, 0);
                acc[tm][tn] = __builtin_amdgcn_mfma_f32_16x16x32_bf16(ah[tm], bl, acc[tm][tn], 0, 0, 0);
                acc[tm][tn] = __builtin_amdgcn_mfma_f32_16x16x32_bf16(al_[tm], bh, acc[tm][tn], 0, 0, 0);
            }
        }
        __syncthreads();
    }

    float* Xb = Xp + (size_t)b * SQ * DV;
    const int quad = lane >> 4;
    const int col  = lane & 15;
#pragma unroll
    for (int tm = 0; tm < 4; ++tm)
#pragma unroll
        for (int tn = 0; tn < 4; ++tn)
#pragma unroll
            for (int r = 0; r < 4; ++r)
                Xb[(size_t)(q0 + wq + tm * 16 + quad * 4 + r) * DV + v0 + wv + tn * 16 + col] = acc[tm][tn][r];
}

// ---------------------------------------------------------------------------
// Kernel 4: in-place masked softmax over last dim (512). One wave per row.
// ---------------------------------------------------------------------------
__global__ __launch_bounds__(256) void softmax_kernel(float* __restrict__ X,
                                                      const int* __restrict__ vlen) {
    const int wave = threadIdx.x >> 6;
    const int lane = threadIdx.x & 63;
    const int row  = blockIdx.x * 4 + wave;
    const int q    = row & (SQ - 1);
    float* xr = X + (size_t)row * DV;
    const int vl = vlen[q];

    float v[8];
#pragma unroll
    for (int u = 0; u < 2; ++u) {
        const int j0 = u * 256 + lane * 4;
        const float4 f = *(const float4*)&xr[j0];
        v[u * 4 + 0] = (j0 + 0 > vl) ? -1.0e6f : f.x;
        v[u * 4 + 1] = (j0 + 1 > vl) ? -1.0e6f : f.y;
        v[u * 4 + 2] = (j0 + 2 > vl) ? -1.0e6f : f.z;
        v[u * 4 + 3] = (j0 + 3 > vl) ? -1.0e6f : f.w;
    }

    float m = v[0];
#pragma unroll
    for (int i = 1; i < 8; ++i) m = fmaxf(m, v[i]);
#pragma unroll
    for (int off = 32; off > 0; off >>= 1) m = fmaxf(m, __shfl_xor(m, off, 64));

    float ssum = 0.f;
#pragma unroll
    for (int i = 0; i < 8; ++i) {
        v[i] = __expf(v[i] - m);
        ssum += v[i];
    }
#pragma unroll
    for (int off = 32; off > 0; off >>= 1) ssum += __shfl_xor(ssum, off, 64);

    const float inv = 1.0f / ssum;
#pragma unroll
    for (int u = 0; u < 2; ++u) {
        const int j0 = u * 256 + lane * 4;
        float4 o;
        o.x = v[u * 4 + 0] * inv;
        o.y = v[u * 4 + 1] * inv;
        o.z = v[u * 4 + 2] * inv;
        o.w = v[u * 4 + 3] * inv;
        *(float4*)&xr[j0] = o;
    }
}

extern "C" void kernel_launch(void* const* d_in, const int* in_sizes, int n_in,
                              void* d_out, int out_size, void* d_ws, size_t ws_size,
                              hipStream_t stream) {
    const float* Kp   = (const float*)d_in[0];
    const float* Vp   = (const float*)d_in[1];
    const float* Qp   = (const float*)d_in[2];
    const int*   vlen = (const int*)d_in[3];
    float* out = (float*)d_out;

    // ws: Mt_hi (4 MB) | Mt_lo (4 MB) -- proven-safe 8 MB footprint.
    unsigned short* Mth = (unsigned short*)d_ws;
    unsigned short* Mtl = Mth + (size_t)BATCH * DD * DV;
    // fp32 partials (4 x 8 MB = 32 MB) live in d_out; overwritten by qm later.
    float* Mpart = out;

    ktv_mfma<<<dim3(4, 4, 32), 256, 0, stream>>>(Kp, Vp, Mpart);
    reduce_cvt<<<dim3(2048), 256, 0, stream>>>(Mpart, Mth, Mtl);
    qm_mfma<<<dim3(16, 4, 8), 256, 0, stream>>>(Qp, Mth, Mtl, out);
    softmax_kernel<<<dim3(BATCH * SQ / 4), 256, 0, stream>>>(out, vlen);
}